// Round 3
// baseline (156.721 us; speedup 1.0000x reference)
//
#include <hip/hip_runtime.h>

// BKT forward scan — FAITHFUL fp32 K-space recurrence.
//
// The reference, run in fp32, has an absorbing state: after ~13 consecutive
// correct answers K rounds to exactly 1.0f and stays pinned forever
// (k_wrong = 0.1/(0.1+0) = 1). An algebraically-exact reformulation (odds
// space) diverges by up to 0.883 (= 1 - fixed point of the wrong-map) on
// rows that pin. So we replicate the reference's fp32 arithmetic bit-exactly:
//   kc  = K*(1-s) / (K*(1-s) + g*(1-K))
//   kw  = K*s     / (K*s     + (1-K)*(1-g))
//   k   = rt==1 ? kc : kw          (same value np.where selects)
//   K'  = k + (1-k)*p
// using __f*_rn intrinsics (IEEE correctly-rounded, no contraction), in the
// reference's evaluation order.
//
// Parallelism: 8192 independent rows, each a 1023-step dependent chain
// (~65 cy/step incl. IEEE div). 2 rows/thread gives 2 independent chains
// (ILP-2 hides the div latency); 256 blocks x 16 threads puts one wave on
// every CU.

static constexpr int BROWS = 8192;
static constexpr int LCOLS = 1024;
static constexpr int LM1   = 1023;

__device__ __forceinline__ float bkt_step(float K, int rt,
                                          float s_, float g_,
                                          float cs, float cg, float p_) {
    const float omK = __fsub_rn(1.0f, K);
    const float A   = (rt == 1) ? cs : s_;   // multiplier on K
    const float Bc  = (rt == 1) ? g_ : cg;   // multiplier on (1-K)
    const float num = __fmul_rn(K, A);
    const float den = __fadd_rn(num, __fmul_rn(Bc, omK));
    const float k   = __fdiv_rn(num, den);
    return __fadd_rn(k, __fmul_rn(__fsub_rn(1.0f, k), p_));
}

__global__ __launch_bounds__(64) void bkt_scan_kernel(
    const int*   __restrict__ resp,
    const float* __restrict__ p_slip,
    const float* __restrict__ p_guess,
    const float* __restrict__ p_train,
    const float* __restrict__ p_learn,
    float*       __restrict__ out)   // [pred (B*LM1) | r_shft (B*LM1)]
{
    const int gid = blockIdx.x * blockDim.x + threadIdx.x;   // 0..4095
    if (gid >= BROWS / 2) return;
    const int r0 = gid * 2;
    const int r1 = r0 + 1;

    const float s_ = *p_slip;
    const float g_ = *p_guess;
    const float p_ = *p_train;
    const float K0 = *p_learn;
    const float cs = __fsub_rn(1.0f, s_);
    const float cg = __fsub_rn(1.0f, g_);

    float Ka = K0;
    float Kb = K0;

    const int4* rowA  = reinterpret_cast<const int4*>(resp + (size_t)r0 * LCOLS);
    const int4* rowB  = reinterpret_cast<const int4*>(resp + (size_t)r1 * LCOLS);
    float* predA = out + (size_t)r0 * LM1;
    float* predB = out + (size_t)r1 * LM1;
    float* rsA   = out + (size_t)BROWS * LM1 + (size_t)r0 * LM1;
    float* rsB   = out + (size_t)BROWS * LM1 + (size_t)r1 * LM1;

    for (int j = 0; j < LCOLS / 4; ++j) {
        const int4 va = rowA[j];
        const int4 vb = rowB[j];
        const int  t0 = 4 * j;

        // r_shft[t] = (float)resp[t+1]
        if (j > 0) { rsA[t0 - 1] = (float)va.x; rsB[t0 - 1] = (float)vb.x; }
        rsA[t0]     = (float)va.y;  rsB[t0]     = (float)vb.y;
        rsA[t0 + 1] = (float)va.z;  rsB[t0 + 1] = (float)vb.z;
        rsA[t0 + 2] = (float)va.w;  rsB[t0 + 2] = (float)vb.w;

        // recurrence: pred[t] = K after consuming resp[t], t <= 1022
        Ka = bkt_step(Ka, va.x, s_, g_, cs, cg, p_);  predA[t0] = Ka;
        Kb = bkt_step(Kb, vb.x, s_, g_, cs, cg, p_);  predB[t0] = Kb;

        Ka = bkt_step(Ka, va.y, s_, g_, cs, cg, p_);  predA[t0 + 1] = Ka;
        Kb = bkt_step(Kb, vb.y, s_, g_, cs, cg, p_);  predB[t0 + 1] = Kb;

        Ka = bkt_step(Ka, va.z, s_, g_, cs, cg, p_);  predA[t0 + 2] = Ka;
        Kb = bkt_step(Kb, vb.z, s_, g_, cs, cg, p_);  predB[t0 + 2] = Kb;

        if (j < LCOLS / 4 - 1) {
            Ka = bkt_step(Ka, va.w, s_, g_, cs, cg, p_);  predA[t0 + 3] = Ka;
            Kb = bkt_step(Kb, vb.w, s_, g_, cs, cg, p_);  predB[t0 + 3] = Kb;
        }
    }
}

extern "C" void kernel_launch(void* const* d_in, const int* in_sizes, int n_in,
                              void* d_out, int out_size, void* d_ws, size_t ws_size,
                              hipStream_t stream) {
    const int*   resp = (const int*)  d_in[0];
    const float* s    = (const float*)d_in[1];
    const float* g    = (const float*)d_in[2];
    const float* tp   = (const float*)d_in[3];
    const float* lp   = (const float*)d_in[4];
    float* out = (float*)d_out;

    // 4096 worker threads (2 rows each), 16 threads/block -> 256 blocks,
    // one wave on each of the 256 CUs.
    bkt_scan_kernel<<<256, 16, 0, stream>>>(resp, s, g, tp, lp, out);
}

// Round 4
// 67.778 us; speedup vs baseline: 2.3123x; 2.3123x over previous
//
#include <hip/hip_runtime.h>

// BKT forward scan — faithful fp32 K-space recurrence, latency-optimized.
//
// Reference semantics (must be replicated to fp32 bit-exactness — the
// recurrence has an absorbing state K==1.0f reached after ~13 consecutive
// correct answers; any algebraic reformulation diverges by up to 0.88):
//   kc = K*(1-s) / (K*(1-s) + g*(1-K))      (taken when rt==1)
//   kw = K*s     / (K*s     + (1-K)*(1-g))  (taken when rt==0)
//   K' = k + (1-k)*p
//
// R4 structure: 1 row/thread (8192 threads = 128 full waves), so each wave
// carries ONE dependent chain — wall-clock = 1023 x per-step chain latency.
// Levers vs R3:
//  - distance-1 prefetch of the int4 response chunk (load off the chain)
//  - division via rcp + 2x Newton + Markstein fma-correction: correctly
//    rounded for our benign operand ranges, no div_scale/div_fmas/div_fixup,
//    no implicit-VCC serialization, ~16cy shorter dependent chain
//  - r_shft (pure cast of resp[:,1:]) fused; its stores fill chain stalls

static constexpr int BROWS = 8192;
static constexpr int LCOLS = 1024;
static constexpr int LM1   = 1023;

// Correctly-rounded u/d for normal, well-scaled operands.
// rcp (<=1ulp) -> 2x Newton (reciprocal converges to RN(1/d) +- eps)
// -> q=RN(u*y) -> exact fma residual -> Markstein correction.
__device__ __forceinline__ float fdiv_cr(float u, float d) {
    float y = __builtin_amdgcn_rcpf(d);
    y = __fmaf_rn(__fmaf_rn(-d, y, 1.0f), y, y);
    y = __fmaf_rn(__fmaf_rn(-d, y, 1.0f), y, y);
    float q = __fmul_rn(u, y);
    float r = __fmaf_rn(-d, q, u);
    return __fmaf_rn(r, y, q);
}

__device__ __forceinline__ float bkt_step(float K, int rt,
                                          float s_, float g_,
                                          float cs, float cg, float p_) {
    const float omK = __fsub_rn(1.0f, K);
    const float A   = (rt == 1) ? cs : s_;   // multiplier on K
    const float Bc  = (rt == 1) ? g_ : cg;   // multiplier on (1-K)
    const float num = __fmul_rn(K, A);
    const float den = __fadd_rn(num, __fmul_rn(Bc, omK));
    const float k   = fdiv_cr(num, den);
    return __fadd_rn(k, __fmul_rn(__fsub_rn(1.0f, k), p_));
}

__global__ __launch_bounds__(64) void bkt_scan_kernel(
    const int*   __restrict__ resp,
    const float* __restrict__ p_slip,
    const float* __restrict__ p_guess,
    const float* __restrict__ p_train,
    const float* __restrict__ p_learn,
    float*       __restrict__ out)   // [pred (B*LM1) | r_shft (B*LM1)]
{
    const int b = blockIdx.x * 64 + threadIdx.x;   // 0..8191, one row each

    const float s_ = *p_slip;
    const float g_ = *p_guess;
    const float p_ = *p_train;
    float       K  = *p_learn;
    const float cs = __fsub_rn(1.0f, s_);
    const float cg = __fsub_rn(1.0f, g_);

    const int4* row  = reinterpret_cast<const int4*>(resp + (size_t)b * LCOLS);
    float*      pred = out + (size_t)b * LM1;
    float*      rs   = out + (size_t)BROWS * LM1 + (size_t)b * LM1;

    int4 v = row[0];
    for (int j = 0; j < LCOLS / 4; ++j) {
        // distance-1 prefetch (clamped so the last row never reads past end)
        const int jn = (j < LCOLS / 4 - 1) ? j + 1 : j;
        const int4 vn = row[jn];

        const int t0 = 4 * j;

        // r_shft[t] = (float)resp[t+1] — stores fill chain-stall slots
        if (j > 0) rs[t0 - 1] = (float)v.x;
        rs[t0]     = (float)v.y;
        rs[t0 + 1] = (float)v.z;
        rs[t0 + 2] = (float)v.w;

        // the dependent chain: pred[t] = K after consuming resp[t]
        K = bkt_step(K, v.x, s_, g_, cs, cg, p_);  pred[t0] = K;
        K = bkt_step(K, v.y, s_, g_, cs, cg, p_);  pred[t0 + 1] = K;
        K = bkt_step(K, v.z, s_, g_, cs, cg, p_);  pred[t0 + 2] = K;
        if (j < LCOLS / 4 - 1) {
            K = bkt_step(K, v.w, s_, g_, cs, cg, p_);  pred[t0 + 3] = K;
        }
        v = vn;
    }
}

extern "C" void kernel_launch(void* const* d_in, const int* in_sizes, int n_in,
                              void* d_out, int out_size, void* d_ws, size_t ws_size,
                              hipStream_t stream) {
    const int*   resp = (const int*)  d_in[0];
    const float* s    = (const float*)d_in[1];
    const float* g    = (const float*)d_in[2];
    const float* tp   = (const float*)d_in[3];
    const float* lp   = (const float*)d_in[4];
    float* out = (float*)d_out;

    bkt_scan_kernel<<<BROWS / 64, 64, 0, stream>>>(resp, s, g, tp, lp, out);
}